// Round 10
// baseline (174.745 us; speedup 1.0000x reference)
//
#include <hip/hip_runtime.h>
#include <stdint.h>

// Match numpy op-for-op rounding: no FMA contraction anywhere.
#pragma clang fp contract(off)

#define BATCH 8
#define HH 64
#define WW 64
#define KA 9
#define NBOX (HH * WW * KA)   // 36864 per batch
#define TOPN 2000
#define NPAD 2048
#define NW 32                 // 64-bit words covering 2048 bits
#define IOU_T 0.7f
#define MINSZ 0.01f
#define EPSF 1e-7f
#define TSTRIDE 33            // LDS tile row stride in u64 (bank-conflict-free)

typedef unsigned int u32;
typedef unsigned long long u64;

__device__ __forceinline__ float clamp01(float x) { return fminf(fmaxf(x, 0.0f), 1.0f); }

// Workgroup barrier with LDS-only drain: does NOT wait vmcnt, so global
// prefetch loads stay in flight across the barrier (the __syncthreads
// vmcnt(0) drain was resolve's per-iteration stall).
__device__ __forceinline__ void bar_lds()
{
    asm volatile("s_waitcnt lgkmcnt(0)" ::: "memory");
    __builtin_amdgcn_s_barrier();
}

// ---------------------------------------------------------------------------
// Shared box decode (bit-exact same arithmetic everywhere; contract off).
// ---------------------------------------------------------------------------
__device__ __forceinline__ void decode_one(
    const float* __restrict__ scores, const float4* __restrict__ offsets,
    const float* __restrict__ anchors, int gid, int t,
    float4* boxOut, u32* keyOut)
{
    int k = t % KA;
    int pos = t / KA;
    int wx = pos & (WW - 1);
    int hy = pos >> 6;
    float s = scores[gid];
    float4 off = offsets[gid];
    float aw = anchors[2 * k], ah = anchors[2 * k + 1];
    float cx = ((float)wx + 0.5f) * 16.0f;
    float cy = ((float)hy + 0.5f) * 16.0f;
    float pw = (expf(off.z) * aw) / 1024.0f;   // exp(off)*anc/img_wh
    float ph = (expf(off.w) * ah) / 1024.0f;
    float xc = (aw * off.x + cx) / 1024.0f;    // (anc*off + center)/img_wh
    float yc = (ah * off.y + cy) / 1024.0f;
    float x1 = clamp01(xc - pw * 0.5f);
    float y1 = clamp01(yc - ph * 0.5f);
    float x2 = clamp01(xc + pw * 0.5f);
    float y2 = clamp01(yc + ph * 0.5f);
    float sc = clamp01(s);
    float m = ((x2 - x1) > MINSZ && (y2 - y1) > MINSZ) ? 1.0f : 0.0f;
    *boxOut = make_float4(x1 * m, y1 * m, x2 * m, y2 * m);
    *keyOut = __float_as_uint(sc * m);   // score >= 0: bit order == value order
}

// ---------------------------------------------------------------------------
// 1) Fused per-batch decode + select: pass 0 decodes score keys (writing them
//    to global scratch for later passes), 3-pass LDS radix (12+12+8 bits)
//    -> exact 32-bit threshold Sstar; compact keys>=Sstar into LDS; bitonic
//    sort 2048 desc ((score<<16)|(0xFFFF-i)); re-decode top-2000 boxes.
//    One block per batch. Same-block global write->read visibility is
//    guaranteed by __syncthreads (workgroup-scope fence, same L1/L2).
// ---------------------------------------------------------------------------
__global__ __launch_bounds__(1024) void select_kernel(
    const float* __restrict__ scores, const float4* __restrict__ offsets,
    const float* __restrict__ anchors, u32* __restrict__ keys,
    float4* __restrict__ topBoxes)
{
    int b = blockIdx.x;
    int tid = threadIdx.x;
    u32* kb = keys + (size_t)b * NBOX;

    __shared__ u32 hist[4096];
    __shared__ u32 suf[1024];
    __shared__ u64 sel[NPAD];
    __shared__ u32 Bsh;
    __shared__ int Rsh;
    __shared__ int ctr;

    if (tid == 0) ctr = 0;
    int r = TOPN;
    u32 P1 = 0, P12 = 0, Sstar = 0;

    for (int pass = 0; pass < 3; ++pass) {
        int nb = (pass < 2) ? 4096 : 256;
        for (int i = tid; i < nb; i += 1024) hist[i] = 0;
        __syncthreads();
        for (int i = tid; i < NBOX; i += 1024) {
            u32 key;
            if (pass == 0) {            // decode + persist key
                float4 box;
                decode_one(scores, offsets, anchors, b * NBOX + i, i, &box, &key);
                kb[i] = key;
                atomicAdd(&hist[key >> 20], 1u);
            } else {
                key = kb[i];
                if (pass == 1) {
                    if ((key >> 20) == P1) atomicAdd(&hist[(key >> 8) & 0xFFFu], 1u);
                } else {
                    if ((key >> 8) == P12) atomicAdd(&hist[key & 0xFFu], 1u);
                }
            }
        }
        __syncthreads();
        // descending-rank find: thread t owns bins [4t, 4t+3]
        int owners = nb / 4;
        if (tid < owners) {
            u32 s = hist[4 * tid] + hist[4 * tid + 1] + hist[4 * tid + 2] + hist[4 * tid + 3];
            suf[tid] = s;
        }
        __syncthreads();
        for (int d = 1; d < owners; d <<= 1) {
            u32 v = (tid < owners && tid + d < owners) ? suf[tid + d] : 0u;
            __syncthreads();
            if (tid < owners) suf[tid] += v;
            __syncthreads();
        }
        if (tid < owners) {
            u32 mine = suf[tid];
            u32 nxt = (tid < owners - 1) ? suf[tid + 1] : 0u;
            if (mine >= (u32)r && nxt < (u32)r) {      // exactly one thread
                u32 cum = nxt;
                for (int v = 4 * tid + 3; v >= 4 * tid; --v) {
                    u32 hv = hist[v];
                    cum += hv;
                    if (cum >= (u32)r) { Bsh = (u32)v; Rsh = r - (int)(cum - hv); break; }
                }
            }
        }
        __syncthreads();
        r = Rsh;
        if (pass == 0)      P1 = Bsh;
        else if (pass == 1) P12 = (P1 << 12) | Bsh;
        else                Sstar = (P12 << 8) | Bsh;
        __syncthreads();   // hist reused next pass
    }

    // compact keys >= Sstar into LDS (slot order arbitrary; sort follows)
    for (int i = tid; i < NPAD; i += 1024) sel[i] = 0ull;
    __syncthreads();
    for (int i = tid; i < NBOX; i += 1024) {
        u32 key = kb[i];
        bool take = (key >= Sstar);
        u64 bal = __ballot(take);
        int base = 0;
        if ((tid & 63) == 0 && bal) base = atomicAdd(&ctr, (int)__popcll(bal));
        base = __shfl(base, 0);
        if (take) {
            int slot = base + (int)__popcll(bal & ((1ull << (tid & 63)) - 1ull));
            if (slot < NPAD)   // safety vs pathological tie counts
                sel[slot] = ((u64)key << 16) | (u64)(0xFFFFu - (u32)i);
        }
    }
    __syncthreads();

    // bitonic sort 2048 desc
    for (int k = 2; k <= NPAD; k <<= 1) {
        for (int j = k >> 1; j > 0; j >>= 1) {
#pragma unroll
            for (int n = 0; n < 2; ++n) {
                int i = tid + n * 1024;
                int ixj = i ^ j;
                if (ixj > i) {
                    bool desc = ((i & k) == 0);
                    u64 a = sel[i], c = sel[ixj];
                    if (desc ? (a < c) : (a > c)) { sel[i] = c; sel[ixj] = a; }
                }
            }
            __syncthreads();
        }
    }

    // re-decode top-2000 boxes; rows 2000..2047 zeroed for safe loads
    for (int i = tid; i < NPAD; i += 1024) {
        float4 v = make_float4(0, 0, 0, 0);
        if (i < TOPN) {
            u64 K = sel[i];
            int idx = 0xFFFF - (int)(K & 0xFFFFull);
            u32 kdummy;
            decode_one(scores, offsets, anchors, b * NBOX + idx, idx, &v, &kdummy);
        }
        topBoxes[b * NPAD + i] = v;
    }
}

// ---------------------------------------------------------------------------
// 2) Suppression bitmask, upper triangle only: row r writes words w >= r>>6.
// ---------------------------------------------------------------------------
__global__ __launch_bounds__(256) void iou_kernel(
    const float4* __restrict__ topBoxes, u64* __restrict__ sup)
{
    int gid = blockIdx.x * 256 + threadIdx.x;
    int wid = gid >> 6;
    int lane = gid & 63;
    int b = wid / TOPN;
    int r = wid - b * TOPN;

    float4 A = topBoxes[(size_t)b * NPAD + r];
    float areaA = (A.z - A.x) * (A.w - A.y);
    size_t supBase = ((size_t)b * NPAD + r) * NW;

    for (int w = r >> 6; w < NW; ++w) {
        int j = w * 64 + lane;
        float4 Bx = topBoxes[(size_t)b * NPAD + j];
        float ix1 = fmaxf(A.x, Bx.x);
        float iy1 = fmaxf(A.y, Bx.y);
        float ix2 = fminf(A.z, Bx.z);
        float iy2 = fminf(A.w, Bx.w);
        float iw = fmaxf(ix2 - ix1, 0.0f);
        float ih = fmaxf(iy2 - iy1, 0.0f);
        float inter = iw * ih;
        float areaB = (Bx.z - Bx.x) * (Bx.w - Bx.y);
        float iou = inter / (areaA + areaB - inter + EPSF);
        bool s = (iou > IOU_T) && (j > r) && (j < TOPN);
        u64 m = __ballot(s);
        if (lane == 0) sup[supBase + w] = m;
    }
}

// ---------------------------------------------------------------------------
// 3) Word-blocked NMS sweep. Double-buffered LDS tiles + 1-ahead register
//    prefetch; lgkm-only barriers keep the prefetch in flight across the
//    whole iteration (the compiler's vmcnt wait lands at the stage point,
//    after phase 2). Phase 1 is forced scalar: keep word readfirstlane'd to
//    SGPRs -> s_ff1 / v_readlane(SGPR idx) / s_andn2_b64 chain.
// ---------------------------------------------------------------------------
__global__ __launch_bounds__(256) void resolve_kernel(
    const u64* __restrict__ sup, const float4* __restrict__ topBoxes,
    float4* __restrict__ out)
{
    int b = blockIdx.x;
    int tid = threadIdx.x;
    __shared__ u64 tile[2][64 * TSTRIDE];   // 2 x 16.9 KB
    __shared__ u64 keep[NW];
    __shared__ int wbase[NW];
    if (tid < NW) keep[tid] = (tid < 31) ? ~0ull : 0xFFFFull;  // bits >=2000 off
    const u64* supB = sup + (size_t)b * NPAD * NW;
    unsigned* keep32 = (unsigned*)keep;

    int row = tid >> 2;               // 0..63
    int wcol = (tid & 3) * 8;         // base word within row (8 consecutive)

    // prologue: load + stage tile 0 (rows 0..63, all 32 words; 16 KB)
    {
        const uint4* src = (const uint4*)(supB + tid * 8);
        uint4 p0 = src[0], p1 = src[1], p2 = src[2], p3 = src[3];
        u64* d = &tile[0][row * TSTRIDE + wcol];
        d[0] = ((u64)p0.y << 32) | p0.x;  d[1] = ((u64)p0.w << 32) | p0.z;
        d[2] = ((u64)p1.y << 32) | p1.x;  d[3] = ((u64)p1.w << 32) | p1.z;
        d[4] = ((u64)p2.y << 32) | p2.x;  d[5] = ((u64)p2.w << 32) | p2.z;
        d[6] = ((u64)p3.y << 32) | p3.x;  d[7] = ((u64)p3.w << 32) | p3.z;
    }
    bar_lds();

    for (int w = 0; w < NW; ++w) {
        int buf = w & 1;
        // issue next tile's loads early (stay in flight across both barriers)
        uint4 n0, n1, n2, n3;
        if (w + 1 < NW) {
            const uint4* src = (const uint4*)(supB + (size_t)(w + 1) * 2048 + tid * 8);
            n0 = src[0]; n1 = src[1]; n2 = src[2]; n3 = src[3];
        }

        // phase 1: wave 0, scalar ffs skip-loop over kept bits only
        if (tid < 64) {
            u64 m = tile[buf][tid * TSTRIDE + w];
            u32 mlo = (u32)m, mhi = (u32)(m >> 32);
            u64 kw64 = keep[w];
            u32 kwlo = (u32)__builtin_amdgcn_readfirstlane((int)(u32)kw64);
            u32 kwhi = (u32)__builtin_amdgcn_readfirstlane((int)(u32)(kw64 >> 32));
            u64 kw = ((u64)kwhi << 32) | kwlo;
            u64 rem = kw;               // kept-and-unprocessed bits
            while (rem) {
                int t2 = (int)(__ffsll((unsigned long long)rem) - 1);
                u32 alo = (u32)__builtin_amdgcn_readlane((int)mlo, t2);
                u32 ahi = (u32)__builtin_amdgcn_readlane((int)mhi, t2);
                u64 mt = ((u64)ahi << 32) | alo;   // bits strictly > t2 only
                kw &= ~mt;
                rem &= ~(mt | (1ull << t2));
            }
            if (tid == 0) keep[w] = kw;
        }
        bar_lds();

        // phase 2: apply kept rows' suppression to later words (from LDS)
        u64 kwword = keep[w];
        int w2 = tid & 31;
        int grp = tid >> 5;              // 8 rows per thread
        if (w2 > w) {
            u64 acc = 0;
#pragma unroll
            for (int q = 0; q < 8; ++q) {
                int rl = grp * 8 + q;
                if ((kwword >> rl) & 1ull)
                    acc |= tile[buf][rl * TSTRIDE + w2];
            }
            if (acc) {
                u32 lo = (u32)acc, hi = (u32)(acc >> 32);
                if (lo) atomicAnd(&keep32[2 * w2], ~lo);
                if (hi) atomicAnd(&keep32[2 * w2 + 1], ~hi);
            }
        }

        // stage next tile into the alternate buffer (prev contents consumed)
        if (w + 1 < NW) {
            u64* d = &tile[buf ^ 1][row * TSTRIDE + wcol];
            d[0] = ((u64)n0.y << 32) | n0.x;  d[1] = ((u64)n0.w << 32) | n0.z;
            d[2] = ((u64)n1.y << 32) | n1.x;  d[3] = ((u64)n1.w << 32) | n1.z;
            d[4] = ((u64)n2.y << 32) | n2.x;  d[5] = ((u64)n2.w << 32) | n2.z;
            d[6] = ((u64)n3.y << 32) | n3.x;  d[7] = ((u64)n3.w << 32) | n3.z;
        }
        bar_lds();
    }

    if (tid == 0) {
        int s = 0;
        for (int w2 = 0; w2 < NW; ++w2) { wbase[w2] = s; s += __popcll(keep[w2]); }
    }
    __syncthreads();
    for (int i = tid; i < TOPN; i += 256)
        out[(size_t)b * TOPN + i] = make_float4(0, 0, 0, 0);
    __syncthreads();
    for (int i = tid; i < TOPN; i += 256) {
        int wi = i >> 6, bz = i & 63;
        u64 kw = keep[wi];
        if ((kw >> bz) & 1ull) {
            int pos = wbase[wi] + __popcll(kw & ((1ull << bz) - 1ull));
            out[(size_t)b * TOPN + pos] = topBoxes[(size_t)b * NPAD + i];
        }
    }
}

// ---------------------------------------------------------------------------
// Workspace layout (bytes):
//   sup      : 0           size 8*2048*32*8 = 4,194,304
//   keys     : 4,194,304   size 8*36864*4   = 1,179,648  (select-internal)
//   topBoxes : 5,373,952   size 8*2048*16   =   262,144
//   total    : 5,636,096 (~5.4 MB); nothing needs pre-zeroing.
// ---------------------------------------------------------------------------
extern "C" void kernel_launch(void* const* d_in, const int* in_sizes, int n_in,
                              void* d_out, int out_size, void* d_ws, size_t ws_size,
                              hipStream_t stream)
{
    const float*  scores  = (const float*)d_in[0];
    const float4* offsets = (const float4*)d_in[1];
    const float*  anchors = (const float*)d_in[2];
    float4* out = (float4*)d_out;

    char* ws = (char*)d_ws;
    u64*    sup      = (u64*)(ws);
    u32*    keys     = (u32*)(ws + 4194304);
    float4* topBoxes = (float4*)(ws + 5373952);

    select_kernel<<<BATCH, 1024, 0, stream>>>(scores, offsets, anchors, keys, topBoxes);
    iou_kernel<<<(BATCH * TOPN * 64) / 256, 256, 0, stream>>>(topBoxes, sup);
    resolve_kernel<<<BATCH, 256, 0, stream>>>(sup, topBoxes, out);
}

// Round 11
// 166.282 us; speedup vs baseline: 1.0509x; 1.0509x over previous
//
#include <hip/hip_runtime.h>
#include <stdint.h>

// Match numpy op-for-op rounding: no FMA contraction anywhere.
#pragma clang fp contract(off)

#define BATCH 8
#define HH 64
#define WW 64
#define KA 9
#define NBOX (HH * WW * KA)   // 36864 per batch
#define TOPN 2000
#define NPAD 2048
#define NW 32                 // 64-bit words covering 2048 bits
#define IOU_T 0.7f
#define MINSZ 0.01f
#define EPSF 1e-7f
#define TSTRIDE 33            // LDS tile row stride in u64 (bank-conflict-free)
#define CANDCAP 3072          // candidate buffer (expected ~2300 for uniform)

typedef unsigned int u32;
typedef unsigned long long u64;

__device__ __forceinline__ float clamp01(float x) { return fminf(fmaxf(x, 0.0f), 1.0f); }

// Workgroup barrier with LDS-only drain: does NOT wait vmcnt, so global
// prefetch loads stay in flight across the barrier.
__device__ __forceinline__ void bar_lds()
{
    asm volatile("s_waitcnt lgkmcnt(0)" ::: "memory");
    __builtin_amdgcn_s_barrier();
}

// ---------------------------------------------------------------------------
// Shared box decode (bit-exact same arithmetic everywhere; contract off).
// ---------------------------------------------------------------------------
__device__ __forceinline__ void decode_one(
    const float* __restrict__ scores, const float4* __restrict__ offsets,
    const float* __restrict__ anchors, int gid, int t,
    float4* boxOut, u32* keyOut)
{
    int k = t % KA;
    int pos = t / KA;
    int wx = pos & (WW - 1);
    int hy = pos >> 6;
    float s = scores[gid];
    float4 off = offsets[gid];
    float aw = anchors[2 * k], ah = anchors[2 * k + 1];
    float cx = ((float)wx + 0.5f) * 16.0f;
    float cy = ((float)hy + 0.5f) * 16.0f;
    float pw = (expf(off.z) * aw) / 1024.0f;   // exp(off)*anc/img_wh
    float ph = (expf(off.w) * ah) / 1024.0f;
    float xc = (aw * off.x + cx) / 1024.0f;    // (anc*off + center)/img_wh
    float yc = (ah * off.y + cy) / 1024.0f;
    float x1 = clamp01(xc - pw * 0.5f);
    float y1 = clamp01(yc - ph * 0.5f);
    float x2 = clamp01(xc + pw * 0.5f);
    float y2 = clamp01(yc + ph * 0.5f);
    float sc = clamp01(s);
    float m = ((x2 - x1) > MINSZ && (y2 - y1) > MINSZ) ? 1.0f : 0.0f;
    *boxOut = make_float4(x1 * m, y1 * m, x2 * m, y2 * m);
    *keyOut = __float_as_uint(sc * m);   // score >= 0: bit order == value order
}

// ---------------------------------------------------------------------------
// 1) Decode score keys only (fully parallel; boxes re-decoded for top-2000).
// ---------------------------------------------------------------------------
__global__ __launch_bounds__(256) void decode_kernel(
    const float* __restrict__ scores, const float4* __restrict__ offsets,
    const float* __restrict__ anchors, u32* __restrict__ keys)
{
    int gid = blockIdx.x * 256 + threadIdx.x;   // grid exactly covers 8*NBOX
    int b = gid / NBOX;
    int t = gid - b * NBOX;
    float4 box; u32 key;
    decode_one(scores, offsets, anchors, gid, t, &box, &key);
    keys[gid] = key;
}

// ---------------------------------------------------------------------------
// 2) Per-batch select, two global streams only:
//    pass 1: 12-bit LDS hist (4096 bins) -> P1 + residual rank r1.
//    pass 2: one stream; definite keys (top12 > P1, exactly 2000-r1) ->
//            sel[]; candidates (top12 == P1, ~2300) -> cand[] (48-bit keys).
//    Then 3x12-bit LDS radix over cand -> exact unique threshold T48;
//    append exactly r1 candidates >= T48. Bitonic sort 2048 desc;
//    re-decode top-2000 boxes. One block per batch.
// ---------------------------------------------------------------------------
__global__ __launch_bounds__(1024) void select_kernel(
    const u32* __restrict__ keys, const float* __restrict__ scores,
    const float4* __restrict__ offsets, const float* __restrict__ anchors,
    float4* __restrict__ topBoxes)
{
    int b = blockIdx.x;
    int tid = threadIdx.x;
    const u32* kb = keys + (size_t)b * NBOX;

    __shared__ u32 hist[4096];   // 16 KB
    __shared__ u32 suf[1024];    //  4 KB
    __shared__ u64 sel[NPAD];    // 16 KB
    __shared__ u64 cand[CANDCAP];// 24 KB  (total ~60.5 KB)
    __shared__ u32 Bsh;
    __shared__ int Rsh;
    __shared__ int ctr, cctr;

    // ---- pass 1: hist over key>>20 ----
    for (int i = tid; i < 4096; i += 1024) hist[i] = 0;
    if (tid == 0) { ctr = 0; cctr = 0; }
    __syncthreads();
    for (int i = tid; i < NBOX; i += 1024)
        atomicAdd(&hist[kb[i] >> 20], 1u);
    __syncthreads();

    // descending-rank find: thread t owns bins [4t, 4t+3]
    int r = TOPN;
    {
        u32 s = hist[4 * tid] + hist[4 * tid + 1] + hist[4 * tid + 2] + hist[4 * tid + 3];
        suf[tid] = s;
        __syncthreads();
        for (int d = 1; d < 1024; d <<= 1) {
            u32 v = (tid + d < 1024) ? suf[tid + d] : 0u;
            __syncthreads();
            suf[tid] += v;
            __syncthreads();
        }
        u32 mine = suf[tid];
        u32 nxt = (tid < 1023) ? suf[tid + 1] : 0u;
        if (mine >= (u32)r && nxt < (u32)r) {      // exactly one thread
            u32 cum = nxt;
            for (int v = 4 * tid + 3; v >= 4 * tid; --v) {
                u32 hv = hist[v];
                cum += hv;
                if (cum >= (u32)r) { Bsh = (u32)v; Rsh = r - (int)(cum - hv); break; }
            }
        }
        __syncthreads();
    }
    u32 P1 = Bsh;
    int r1 = Rsh;          // need top-r1 of the candidates (top12 == P1)
    __syncthreads();

    // ---- pass 2: definite -> sel, candidates -> cand ----
    for (int i = tid; i < NPAD; i += 1024) sel[i] = 0ull;
    __syncthreads();
    int lane = tid & 63;
    for (int i = tid; i < NBOX; i += 1024) {
        u32 key = kb[i];
        u32 top = key >> 20;
        u64 K = ((u64)key << 16) | (u64)(0xFFFFu - (u32)i);
        bool def = (top > P1);
        bool cnd = (top == P1);
        u64 bd = __ballot(def);
        u64 bc = __ballot(cnd);
        int based = 0, basec = 0;
        if (lane == 0) {
            if (bd) based = atomicAdd(&ctr, (int)__popcll(bd));
            if (bc) basec = atomicAdd(&cctr, (int)__popcll(bc));
        }
        based = __shfl(based, 0);
        basec = __shfl(basec, 0);
        if (def) {
            int slot = based + (int)__popcll(bd & ((1ull << lane) - 1ull));
            if (slot < NPAD) sel[slot] = K;
        }
        if (cnd) {
            int cslot = basec + (int)__popcll(bc & ((1ull << lane) - 1ull));
            if (cslot < CANDCAP) cand[cslot] = K;
        }
    }
    __syncthreads();
    int cc = cctr < CANDCAP ? cctr : CANDCAP;

    // ---- 3x12-bit LDS radix over candidates: exact T48 ----
    u64 prefix = (u64)P1;               // == K>>36 for every candidate
    r = r1;
    for (int p = 0; p < 3; ++p) {
        int shift = 24 - 12 * p;
        for (int i = tid; i < 4096; i += 1024) hist[i] = 0;
        __syncthreads();
        for (int c = tid; c < cc; c += 1024) {
            u64 K = cand[c];
            if ((K >> (shift + 12)) == prefix)
                atomicAdd(&hist[(u32)((K >> shift) & 0xFFFull)], 1u);
        }
        __syncthreads();
        u32 s = hist[4 * tid] + hist[4 * tid + 1] + hist[4 * tid + 2] + hist[4 * tid + 3];
        suf[tid] = s;
        __syncthreads();
        for (int d = 1; d < 1024; d <<= 1) {
            u32 v = (tid + d < 1024) ? suf[tid + d] : 0u;
            __syncthreads();
            suf[tid] += v;
            __syncthreads();
        }
        u32 mine = suf[tid];
        u32 nxt = (tid < 1023) ? suf[tid + 1] : 0u;
        if (mine >= (u32)r && nxt < (u32)r) {
            u32 cum = nxt;
            for (int v = 4 * tid + 3; v >= 4 * tid; --v) {
                u32 hv = hist[v];
                cum += hv;
                if (cum >= (u32)r) { Bsh = (u32)v; Rsh = r - (int)(cum - hv); break; }
            }
        }
        __syncthreads();
        prefix = (prefix << 12) | (u64)Bsh;
        r = Rsh;
        __syncthreads();
    }
    u64 T48 = prefix;   // exact r1-th largest candidate key (unique keys)

    // append exactly r1 candidates >= T48
    for (int c = tid; c < cc; c += 1024) {
        u64 K = cand[c];
        bool take = (K >= T48);
        u64 bal = __ballot(take);
        int base = 0;
        if (lane == 0 && bal) base = atomicAdd(&ctr, (int)__popcll(bal));
        base = __shfl(base, 0);
        if (take) {
            int slot = base + (int)__popcll(bal & ((1ull << lane) - 1ull));
            if (slot < NPAD) sel[slot] = K;
        }
    }
    __syncthreads();

    // ---- bitonic sort 2048 desc ----
    for (int k = 2; k <= NPAD; k <<= 1) {
        for (int j = k >> 1; j > 0; j >>= 1) {
#pragma unroll
            for (int n = 0; n < 2; ++n) {
                int i = tid + n * 1024;
                int ixj = i ^ j;
                if (ixj > i) {
                    bool desc = ((i & k) == 0);
                    u64 a = sel[i], c = sel[ixj];
                    if (desc ? (a < c) : (a > c)) { sel[i] = c; sel[ixj] = a; }
                }
            }
            __syncthreads();
        }
    }

    // re-decode top-2000 boxes; rows 2000..2047 zeroed for safe loads
    for (int i = tid; i < NPAD; i += 1024) {
        float4 v = make_float4(0, 0, 0, 0);
        if (i < TOPN) {
            u64 K = sel[i];
            int idx = 0xFFFF - (int)(K & 0xFFFFull);
            u32 kdummy;
            decode_one(scores, offsets, anchors, b * NBOX + idx, idx, &v, &kdummy);
        }
        topBoxes[b * NPAD + i] = v;
    }
}

// ---------------------------------------------------------------------------
// 3) Suppression bitmask, upper triangle only: row r writes words w >= r>>6.
// ---------------------------------------------------------------------------
__global__ __launch_bounds__(256) void iou_kernel(
    const float4* __restrict__ topBoxes, u64* __restrict__ sup)
{
    int gid = blockIdx.x * 256 + threadIdx.x;
    int wid = gid >> 6;
    int lane = gid & 63;
    int b = wid / TOPN;
    int r = wid - b * TOPN;

    float4 A = topBoxes[(size_t)b * NPAD + r];
    float areaA = (A.z - A.x) * (A.w - A.y);
    size_t supBase = ((size_t)b * NPAD + r) * NW;

    for (int w = r >> 6; w < NW; ++w) {
        int j = w * 64 + lane;
        float4 Bx = topBoxes[(size_t)b * NPAD + j];
        float ix1 = fmaxf(A.x, Bx.x);
        float iy1 = fmaxf(A.y, Bx.y);
        float ix2 = fminf(A.z, Bx.z);
        float iy2 = fminf(A.w, Bx.w);
        float iw = fmaxf(ix2 - ix1, 0.0f);
        float ih = fmaxf(iy2 - iy1, 0.0f);
        float inter = iw * ih;
        float areaB = (Bx.z - Bx.x) * (Bx.w - Bx.y);
        float iou = inter / (areaA + areaB - inter + EPSF);
        bool s = (iou > IOU_T) && (j > r) && (j < TOPN);
        u64 m = __ballot(s);
        if (lane == 0) sup[supBase + w] = m;
    }
}

// ---------------------------------------------------------------------------
// 4) Word-blocked NMS sweep. Double-buffered LDS tiles + 1-ahead register
//    prefetch; lgkm-only barriers keep the prefetch in flight across the
//    whole iteration. Phase 1 scalar ffs skip-loop (SGPR chain).
// ---------------------------------------------------------------------------
__global__ __launch_bounds__(256) void resolve_kernel(
    const u64* __restrict__ sup, const float4* __restrict__ topBoxes,
    float4* __restrict__ out)
{
    int b = blockIdx.x;
    int tid = threadIdx.x;
    __shared__ u64 tile[2][64 * TSTRIDE];   // 2 x 16.9 KB
    __shared__ u64 keep[NW];
    __shared__ int wbase[NW];
    if (tid < NW) keep[tid] = (tid < 31) ? ~0ull : 0xFFFFull;  // bits >=2000 off
    const u64* supB = sup + (size_t)b * NPAD * NW;
    unsigned* keep32 = (unsigned*)keep;

    int row = tid >> 2;               // 0..63
    int wcol = (tid & 3) * 8;         // base word within row (8 consecutive)

    // prologue: load + stage tile 0 (rows 0..63, all 32 words; 16 KB)
    {
        const uint4* src = (const uint4*)(supB + tid * 8);
        uint4 p0 = src[0], p1 = src[1], p2 = src[2], p3 = src[3];
        u64* d = &tile[0][row * TSTRIDE + wcol];
        d[0] = ((u64)p0.y << 32) | p0.x;  d[1] = ((u64)p0.w << 32) | p0.z;
        d[2] = ((u64)p1.y << 32) | p1.x;  d[3] = ((u64)p1.w << 32) | p1.z;
        d[4] = ((u64)p2.y << 32) | p2.x;  d[5] = ((u64)p2.w << 32) | p2.z;
        d[6] = ((u64)p3.y << 32) | p3.x;  d[7] = ((u64)p3.w << 32) | p3.z;
    }
    bar_lds();

    for (int w = 0; w < NW; ++w) {
        int buf = w & 1;
        // issue next tile's loads early (stay in flight across both barriers)
        uint4 n0, n1, n2, n3;
        if (w + 1 < NW) {
            const uint4* src = (const uint4*)(supB + (size_t)(w + 1) * 2048 + tid * 8);
            n0 = src[0]; n1 = src[1]; n2 = src[2]; n3 = src[3];
        }

        // phase 1: wave 0, scalar ffs skip-loop over kept bits only
        if (tid < 64) {
            u64 m = tile[buf][tid * TSTRIDE + w];
            u32 mlo = (u32)m, mhi = (u32)(m >> 32);
            u64 kw64 = keep[w];
            u32 kwlo = (u32)__builtin_amdgcn_readfirstlane((int)(u32)kw64);
            u32 kwhi = (u32)__builtin_amdgcn_readfirstlane((int)(u32)(kw64 >> 32));
            u64 kw = ((u64)kwhi << 32) | kwlo;
            u64 rem = kw;               // kept-and-unprocessed bits
            while (rem) {
                int t2 = (int)(__ffsll((unsigned long long)rem) - 1);
                u32 alo = (u32)__builtin_amdgcn_readlane((int)mlo, t2);
                u32 ahi = (u32)__builtin_amdgcn_readlane((int)mhi, t2);
                u64 mt = ((u64)ahi << 32) | alo;   // bits strictly > t2 only
                kw &= ~mt;
                rem &= ~(mt | (1ull << t2));
            }
            if (tid == 0) keep[w] = kw;
        }
        bar_lds();

        // phase 2: apply kept rows' suppression to later words (from LDS)
        u64 kwword = keep[w];
        int w2 = tid & 31;
        int grp = tid >> 5;              // 8 rows per thread
        if (w2 > w) {
            u64 acc = 0;
#pragma unroll
            for (int q = 0; q < 8; ++q) {
                int rl = grp * 8 + q;
                if ((kwword >> rl) & 1ull)
                    acc |= tile[buf][rl * TSTRIDE + w2];
            }
            if (acc) {
                u32 lo = (u32)acc, hi = (u32)(acc >> 32);
                if (lo) atomicAnd(&keep32[2 * w2], ~lo);
                if (hi) atomicAnd(&keep32[2 * w2 + 1], ~hi);
            }
        }

        // stage next tile into the alternate buffer (prev contents consumed)
        if (w + 1 < NW) {
            u64* d = &tile[buf ^ 1][row * TSTRIDE + wcol];
            d[0] = ((u64)n0.y << 32) | n0.x;  d[1] = ((u64)n0.w << 32) | n0.z;
            d[2] = ((u64)n1.y << 32) | n1.x;  d[3] = ((u64)n1.w << 32) | n1.z;
            d[4] = ((u64)n2.y << 32) | n2.x;  d[5] = ((u64)n2.w << 32) | n2.z;
            d[6] = ((u64)n3.y << 32) | n3.x;  d[7] = ((u64)n3.w << 32) | n3.z;
        }
        bar_lds();
    }

    if (tid == 0) {
        int s = 0;
        for (int w2 = 0; w2 < NW; ++w2) { wbase[w2] = s; s += __popcll(keep[w2]); }
    }
    __syncthreads();
    for (int i = tid; i < TOPN; i += 256)
        out[(size_t)b * TOPN + i] = make_float4(0, 0, 0, 0);
    __syncthreads();
    for (int i = tid; i < TOPN; i += 256) {
        int wi = i >> 6, bz = i & 63;
        u64 kw = keep[wi];
        if ((kw >> bz) & 1ull) {
            int pos = wbase[wi] + __popcll(kw & ((1ull << bz) - 1ull));
            out[(size_t)b * TOPN + pos] = topBoxes[(size_t)b * NPAD + i];
        }
    }
}

// ---------------------------------------------------------------------------
// Workspace layout (bytes):
//   sup      : 0           size 8*2048*32*8 = 4,194,304
//   keys     : 4,194,304   size 8*36864*4   = 1,179,648
//   topBoxes : 5,373,952   size 8*2048*16   =   262,144
//   total    : 5,636,096 (~5.4 MB); nothing needs pre-zeroing.
// ---------------------------------------------------------------------------
extern "C" void kernel_launch(void* const* d_in, const int* in_sizes, int n_in,
                              void* d_out, int out_size, void* d_ws, size_t ws_size,
                              hipStream_t stream)
{
    const float*  scores  = (const float*)d_in[0];
    const float4* offsets = (const float4*)d_in[1];
    const float*  anchors = (const float*)d_in[2];
    float4* out = (float4*)d_out;

    char* ws = (char*)d_ws;
    u64*    sup      = (u64*)(ws);
    u32*    keys     = (u32*)(ws + 4194304);
    float4* topBoxes = (float4*)(ws + 5373952);

    decode_kernel<<<(BATCH * NBOX) / 256, 256, 0, stream>>>(scores, offsets, anchors, keys);
    select_kernel<<<BATCH, 1024, 0, stream>>>(keys, scores, offsets, anchors, topBoxes);
    iou_kernel<<<(BATCH * TOPN * 64) / 256, 256, 0, stream>>>(topBoxes, sup);
    resolve_kernel<<<BATCH, 256, 0, stream>>>(sup, topBoxes, out);
}

// Round 12
// 124.419 us; speedup vs baseline: 1.4045x; 1.3365x over previous
//
#include <hip/hip_runtime.h>
#include <stdint.h>

// Match numpy op-for-op rounding: no FMA contraction anywhere.
#pragma clang fp contract(off)

#define BATCH 8
#define HH 64
#define WW 64
#define KA 9
#define NBOX (HH * WW * KA)   // 36864 per batch
#define TOPN 2000
#define NPAD 2048
#define NW 32                 // 64-bit words covering 2048 bits
#define IOU_T 0.7f
#define MINSZ 0.01f
#define EPSF 1e-7f
#define TSTRIDE 33            // LDS tile row stride in u64 (bank-conflict-free)
#define CANDCAP 3072          // candidate buffer (expected ~2300 for uniform)

typedef unsigned int u32;
typedef unsigned long long u64;

__device__ __forceinline__ float clamp01(float x) { return fminf(fmaxf(x, 0.0f), 1.0f); }

// Workgroup barrier with LDS-only drain: does NOT wait vmcnt, so global
// prefetch loads stay in flight across the barrier.
__device__ __forceinline__ void bar_lds()
{
    asm volatile("s_waitcnt lgkmcnt(0)" ::: "memory");
    __builtin_amdgcn_s_barrier();
}

// ---------------------------------------------------------------------------
// Shared box decode (bit-exact same arithmetic everywhere; contract off).
// ---------------------------------------------------------------------------
__device__ __forceinline__ void decode_one(
    const float* __restrict__ scores, const float4* __restrict__ offsets,
    const float* __restrict__ anchors, int gid, int t,
    float4* boxOut, u32* keyOut)
{
    int k = t % KA;
    int pos = t / KA;
    int wx = pos & (WW - 1);
    int hy = pos >> 6;
    float s = scores[gid];
    float4 off = offsets[gid];
    float aw = anchors[2 * k], ah = anchors[2 * k + 1];
    float cx = ((float)wx + 0.5f) * 16.0f;
    float cy = ((float)hy + 0.5f) * 16.0f;
    float pw = (expf(off.z) * aw) / 1024.0f;   // exp(off)*anc/img_wh
    float ph = (expf(off.w) * ah) / 1024.0f;
    float xc = (aw * off.x + cx) / 1024.0f;    // (anc*off + center)/img_wh
    float yc = (ah * off.y + cy) / 1024.0f;
    float x1 = clamp01(xc - pw * 0.5f);
    float y1 = clamp01(yc - ph * 0.5f);
    float x2 = clamp01(xc + pw * 0.5f);
    float y2 = clamp01(yc + ph * 0.5f);
    float sc = clamp01(s);
    float m = ((x2 - x1) > MINSZ && (y2 - y1) > MINSZ) ? 1.0f : 0.0f;
    *boxOut = make_float4(x1 * m, y1 * m, x2 * m, y2 * m);
    *keyOut = __float_as_uint(sc * m);   // score >= 0: bit order == value order
}

// ---------------------------------------------------------------------------
// 1) Decode score keys only (fully parallel; boxes re-decoded for top-2000).
// ---------------------------------------------------------------------------
__global__ __launch_bounds__(256) void decode_kernel(
    const float* __restrict__ scores, const float4* __restrict__ offsets,
    const float* __restrict__ anchors, u32* __restrict__ keys)
{
    int gid = blockIdx.x * 256 + threadIdx.x;   // grid exactly covers 8*NBOX
    int b = gid / NBOX;
    int t = gid - b * NBOX;
    float4 box; u32 key;
    decode_one(scores, offsets, anchors, gid, t, &box, &key);
    keys[gid] = key;
}

// ---------------------------------------------------------------------------
// 2) Per-batch select, two global streams only (12-bit hist -> P1/r1;
//    definite/candidate split; 3x12-bit LDS radix over candidates -> T48;
//    bitonic sort 2048 desc; re-decode top-2000 boxes).
// ---------------------------------------------------------------------------
__global__ __launch_bounds__(1024) void select_kernel(
    const u32* __restrict__ keys, const float* __restrict__ scores,
    const float4* __restrict__ offsets, const float* __restrict__ anchors,
    float4* __restrict__ topBoxes)
{
    int b = blockIdx.x;
    int tid = threadIdx.x;
    const u32* kb = keys + (size_t)b * NBOX;

    __shared__ u32 hist[4096];   // 16 KB
    __shared__ u32 suf[1024];    //  4 KB
    __shared__ u64 sel[NPAD];    // 16 KB
    __shared__ u64 cand[CANDCAP];// 24 KB  (total ~60.5 KB)
    __shared__ u32 Bsh;
    __shared__ int Rsh;
    __shared__ int ctr, cctr;

    // ---- pass 1: hist over key>>20 ----
    for (int i = tid; i < 4096; i += 1024) hist[i] = 0;
    if (tid == 0) { ctr = 0; cctr = 0; }
    __syncthreads();
    for (int i = tid; i < NBOX; i += 1024)
        atomicAdd(&hist[kb[i] >> 20], 1u);
    __syncthreads();

    // descending-rank find: thread t owns bins [4t, 4t+3]
    int r = TOPN;
    {
        u32 s = hist[4 * tid] + hist[4 * tid + 1] + hist[4 * tid + 2] + hist[4 * tid + 3];
        suf[tid] = s;
        __syncthreads();
        for (int d = 1; d < 1024; d <<= 1) {
            u32 v = (tid + d < 1024) ? suf[tid + d] : 0u;
            __syncthreads();
            suf[tid] += v;
            __syncthreads();
        }
        u32 mine = suf[tid];
        u32 nxt = (tid < 1023) ? suf[tid + 1] : 0u;
        if (mine >= (u32)r && nxt < (u32)r) {      // exactly one thread
            u32 cum = nxt;
            for (int v = 4 * tid + 3; v >= 4 * tid; --v) {
                u32 hv = hist[v];
                cum += hv;
                if (cum >= (u32)r) { Bsh = (u32)v; Rsh = r - (int)(cum - hv); break; }
            }
        }
        __syncthreads();
    }
    u32 P1 = Bsh;
    int r1 = Rsh;          // need top-r1 of the candidates (top12 == P1)
    __syncthreads();

    // ---- pass 2: definite -> sel, candidates -> cand ----
    for (int i = tid; i < NPAD; i += 1024) sel[i] = 0ull;
    __syncthreads();
    int lane = tid & 63;
    for (int i = tid; i < NBOX; i += 1024) {
        u32 key = kb[i];
        u32 top = key >> 20;
        u64 K = ((u64)key << 16) | (u64)(0xFFFFu - (u32)i);
        bool def = (top > P1);
        bool cnd = (top == P1);
        u64 bd = __ballot(def);
        u64 bc = __ballot(cnd);
        int based = 0, basec = 0;
        if (lane == 0) {
            if (bd) based = atomicAdd(&ctr, (int)__popcll(bd));
            if (bc) basec = atomicAdd(&cctr, (int)__popcll(bc));
        }
        based = __shfl(based, 0);
        basec = __shfl(basec, 0);
        if (def) {
            int slot = based + (int)__popcll(bd & ((1ull << lane) - 1ull));
            if (slot < NPAD) sel[slot] = K;
        }
        if (cnd) {
            int cslot = basec + (int)__popcll(bc & ((1ull << lane) - 1ull));
            if (cslot < CANDCAP) cand[cslot] = K;
        }
    }
    __syncthreads();
    int cc = cctr < CANDCAP ? cctr : CANDCAP;

    // ---- 3x12-bit LDS radix over candidates: exact T48 ----
    u64 prefix = (u64)P1;               // == K>>36 for every candidate
    r = r1;
    for (int p = 0; p < 3; ++p) {
        int shift = 24 - 12 * p;
        for (int i = tid; i < 4096; i += 1024) hist[i] = 0;
        __syncthreads();
        for (int c = tid; c < cc; c += 1024) {
            u64 K = cand[c];
            if ((K >> (shift + 12)) == prefix)
                atomicAdd(&hist[(u32)((K >> shift) & 0xFFFull)], 1u);
        }
        __syncthreads();
        u32 s = hist[4 * tid] + hist[4 * tid + 1] + hist[4 * tid + 2] + hist[4 * tid + 3];
        suf[tid] = s;
        __syncthreads();
        for (int d = 1; d < 1024; d <<= 1) {
            u32 v = (tid + d < 1024) ? suf[tid + d] : 0u;
            __syncthreads();
            suf[tid] += v;
            __syncthreads();
        }
        u32 mine = suf[tid];
        u32 nxt = (tid < 1023) ? suf[tid + 1] : 0u;
        if (mine >= (u32)r && nxt < (u32)r) {
            u32 cum = nxt;
            for (int v = 4 * tid + 3; v >= 4 * tid; --v) {
                u32 hv = hist[v];
                cum += hv;
                if (cum >= (u32)r) { Bsh = (u32)v; Rsh = r - (int)(cum - hv); break; }
            }
        }
        __syncthreads();
        prefix = (prefix << 12) | (u64)Bsh;
        r = Rsh;
        __syncthreads();
    }
    u64 T48 = prefix;   // exact r1-th largest candidate key (unique keys)

    // append exactly r1 candidates >= T48
    for (int c = tid; c < cc; c += 1024) {
        u64 K = cand[c];
        bool take = (K >= T48);
        u64 bal = __ballot(take);
        int base = 0;
        if (lane == 0 && bal) base = atomicAdd(&ctr, (int)__popcll(bal));
        base = __shfl(base, 0);
        if (take) {
            int slot = base + (int)__popcll(bal & ((1ull << lane) - 1ull));
            if (slot < NPAD) sel[slot] = K;
        }
    }
    __syncthreads();

    // ---- bitonic sort 2048 desc ----
    for (int k = 2; k <= NPAD; k <<= 1) {
        for (int j = k >> 1; j > 0; j >>= 1) {
#pragma unroll
            for (int n = 0; n < 2; ++n) {
                int i = tid + n * 1024;
                int ixj = i ^ j;
                if (ixj > i) {
                    bool desc = ((i & k) == 0);
                    u64 a = sel[i], c = sel[ixj];
                    if (desc ? (a < c) : (a > c)) { sel[i] = c; sel[ixj] = a; }
                }
            }
            __syncthreads();
        }
    }

    // re-decode top-2000 boxes; rows 2000..2047 zeroed for safe loads
    for (int i = tid; i < NPAD; i += 1024) {
        float4 v = make_float4(0, 0, 0, 0);
        if (i < TOPN) {
            u64 K = sel[i];
            int idx = 0xFFFF - (int)(K & 0xFFFFull);
            u32 kdummy;
            decode_one(scores, offsets, anchors, b * NBOX + idx, idx, &v, &kdummy);
        }
        topBoxes[b * NPAD + i] = v;
    }
}

// ---------------------------------------------------------------------------
// 3) Suppression bitmask, upper triangle only: row r writes words w >= r>>6.
// ---------------------------------------------------------------------------
__global__ __launch_bounds__(256) void iou_kernel(
    const float4* __restrict__ topBoxes, u64* __restrict__ sup)
{
    int gid = blockIdx.x * 256 + threadIdx.x;
    int wid = gid >> 6;
    int lane = gid & 63;
    int b = wid / TOPN;
    int r = wid - b * TOPN;

    float4 A = topBoxes[(size_t)b * NPAD + r];
    float areaA = (A.z - A.x) * (A.w - A.y);
    size_t supBase = ((size_t)b * NPAD + r) * NW;

    for (int w = r >> 6; w < NW; ++w) {
        int j = w * 64 + lane;
        float4 Bx = topBoxes[(size_t)b * NPAD + j];
        float ix1 = fmaxf(A.x, Bx.x);
        float iy1 = fmaxf(A.y, Bx.y);
        float ix2 = fminf(A.z, Bx.z);
        float iy2 = fminf(A.w, Bx.w);
        float iw = fmaxf(ix2 - ix1, 0.0f);
        float ih = fmaxf(iy2 - iy1, 0.0f);
        float inter = iw * ih;
        float areaB = (Bx.z - Bx.x) * (Bx.w - Bx.y);
        float iou = inter / (areaA + areaB - inter + EPSF);
        bool s = (iou > IOU_T) && (j > r) && (j < TOPN);
        u64 m = __ballot(s);
        if (lane == 0) sup[supBase + w] = m;
    }
}

// ---------------------------------------------------------------------------
// 4) Word-blocked NMS sweep. Double-buffered LDS tiles + 1-ahead register
//    prefetch; lgkm-only barriers. Phase 1's serial chain now visits ONLY
//    kept bits whose suppression mask is nonzero: one __ballot(m!=0) gives
//    the suppressor bitmap, so chain length == #kept-suppressors, not #kept
//    (identity steps of zero-mask boxes are provably no-ops).
// ---------------------------------------------------------------------------
__global__ __launch_bounds__(256) void resolve_kernel(
    const u64* __restrict__ sup, const float4* __restrict__ topBoxes,
    float4* __restrict__ out)
{
    int b = blockIdx.x;
    int tid = threadIdx.x;
    __shared__ u64 tile[2][64 * TSTRIDE];   // 2 x 16.9 KB
    __shared__ u64 keep[NW];
    __shared__ u64 nzmap[NW];               // per word: bits with m != 0
    __shared__ int wbase[NW];
    if (tid < NW) keep[tid] = (tid < 31) ? ~0ull : 0xFFFFull;  // bits >=2000 off
    const u64* supB = sup + (size_t)b * NPAD * NW;
    unsigned* keep32 = (unsigned*)keep;

    int row = tid >> 2;               // 0..63
    int wcol = (tid & 3) * 8;         // base word within row (8 consecutive)

    // prologue: load + stage tile 0 (rows 0..63, all 32 words; 16 KB)
    {
        const uint4* src = (const uint4*)(supB + tid * 8);
        uint4 p0 = src[0], p1 = src[1], p2 = src[2], p3 = src[3];
        u64* d = &tile[0][row * TSTRIDE + wcol];
        d[0] = ((u64)p0.y << 32) | p0.x;  d[1] = ((u64)p0.w << 32) | p0.z;
        d[2] = ((u64)p1.y << 32) | p1.x;  d[3] = ((u64)p1.w << 32) | p1.z;
        d[4] = ((u64)p2.y << 32) | p2.x;  d[5] = ((u64)p2.w << 32) | p2.z;
        d[6] = ((u64)p3.y << 32) | p3.x;  d[7] = ((u64)p3.w << 32) | p3.z;
    }
    bar_lds();

    for (int w = 0; w < NW; ++w) {
        int buf = w & 1;
        // issue next tile's loads early (stay in flight across both barriers)
        uint4 n0, n1, n2, n3;
        if (w + 1 < NW) {
            const uint4* src = (const uint4*)(supB + (size_t)(w + 1) * 2048 + tid * 8);
            n0 = src[0]; n1 = src[1]; n2 = src[2]; n3 = src[3];
        }

        // phase 1: wave 0 — serial chain over kept SUPPRESSOR bits only.
        // Lane t also records whether its row has any later-word suppression
        // (for gating phase 2).
        if (tid < 64) {
            u64 m = tile[buf][tid * TSTRIDE + w];
            // does this row suppress anything in words > w?
            u64 later = 0;
            for (int w2 = w + 1; w2 < NW; ++w2) later |= tile[buf][tid * TSTRIDE + w2];
            u64 nzAny = __ballot((m | later) != 0ull);   // rows needing phase 2
            u64 nzDiag = __ballot(m != 0ull);            // rows acting in-word
            u32 mlo = (u32)m, mhi = (u32)(m >> 32);
            u64 kw64 = keep[w];
            u32 kwlo = (u32)__builtin_amdgcn_readfirstlane((int)(u32)kw64);
            u32 kwhi = (u32)__builtin_amdgcn_readfirstlane((int)(u32)(kw64 >> 32));
            u64 kw = ((u64)kwhi << 32) | kwlo;
            u64 rem = kw & nzDiag;          // kept bits that suppress in-word
            while (rem) {
                int t2 = (int)(__ffsll((unsigned long long)rem) - 1);
                u32 alo = (u32)__builtin_amdgcn_readlane((int)mlo, t2);
                u32 ahi = (u32)__builtin_amdgcn_readlane((int)mhi, t2);
                u64 mt = ((u64)ahi << 32) | alo;   // bits strictly > t2 only
                kw &= ~mt;
                rem &= ~(mt | (1ull << t2));
            }
            if (tid == 0) { keep[w] = kw; nzmap[w] = nzAny; }
        }
        bar_lds();

        // phase 2: apply kept suppressor rows to later words (from LDS);
        // rows with no later-word bits are skipped via the nz gate.
        u64 gate = keep[w] & nzmap[w];
        int w2 = tid & 31;
        int grp = tid >> 5;              // 8 rows per thread
        if (w2 > w && gate) {
            u64 acc = 0;
#pragma unroll
            for (int q = 0; q < 8; ++q) {
                int rl = grp * 8 + q;
                if ((gate >> rl) & 1ull)
                    acc |= tile[buf][rl * TSTRIDE + w2];
            }
            if (acc) {
                u32 lo = (u32)acc, hi = (u32)(acc >> 32);
                if (lo) atomicAnd(&keep32[2 * w2], ~lo);
                if (hi) atomicAnd(&keep32[2 * w2 + 1], ~hi);
            }
        }

        // stage next tile into the alternate buffer (prev contents consumed)
        if (w + 1 < NW) {
            u64* d = &tile[buf ^ 1][row * TSTRIDE + wcol];
            d[0] = ((u64)n0.y << 32) | n0.x;  d[1] = ((u64)n0.w << 32) | n0.z;
            d[2] = ((u64)n1.y << 32) | n1.x;  d[3] = ((u64)n1.w << 32) | n1.z;
            d[4] = ((u64)n2.y << 32) | n2.x;  d[5] = ((u64)n2.w << 32) | n2.z;
            d[6] = ((u64)n3.y << 32) | n3.x;  d[7] = ((u64)n3.w << 32) | n3.z;
        }
        bar_lds();
    }

    if (tid == 0) {
        int s = 0;
        for (int w2 = 0; w2 < NW; ++w2) { wbase[w2] = s; s += __popcll(keep[w2]); }
    }
    __syncthreads();
    for (int i = tid; i < TOPN; i += 256)
        out[(size_t)b * TOPN + i] = make_float4(0, 0, 0, 0);
    __syncthreads();
    for (int i = tid; i < TOPN; i += 256) {
        int wi = i >> 6, bz = i & 63;
        u64 kw = keep[wi];
        if ((kw >> bz) & 1ull) {
            int pos = wbase[wi] + __popcll(kw & ((1ull << bz) - 1ull));
            out[(size_t)b * TOPN + pos] = topBoxes[(size_t)b * NPAD + i];
        }
    }
}

// ---------------------------------------------------------------------------
// Workspace layout (bytes):
//   sup      : 0           size 8*2048*32*8 = 4,194,304
//   keys     : 4,194,304   size 8*36864*4   = 1,179,648
//   topBoxes : 5,373,952   size 8*2048*16   =   262,144
//   total    : 5,636,096 (~5.4 MB); nothing needs pre-zeroing.
// ---------------------------------------------------------------------------
extern "C" void kernel_launch(void* const* d_in, const int* in_sizes, int n_in,
                              void* d_out, int out_size, void* d_ws, size_t ws_size,
                              hipStream_t stream)
{
    const float*  scores  = (const float*)d_in[0];
    const float4* offsets = (const float4*)d_in[1];
    const float*  anchors = (const float*)d_in[2];
    float4* out = (float4*)d_out;

    char* ws = (char*)d_ws;
    u64*    sup      = (u64*)(ws);
    u32*    keys     = (u32*)(ws + 4194304);
    float4* topBoxes = (float4*)(ws + 5373952);

    decode_kernel<<<(BATCH * NBOX) / 256, 256, 0, stream>>>(scores, offsets, anchors, keys);
    select_kernel<<<BATCH, 1024, 0, stream>>>(keys, scores, offsets, anchors, topBoxes);
    iou_kernel<<<(BATCH * TOPN * 64) / 256, 256, 0, stream>>>(topBoxes, sup);
    resolve_kernel<<<BATCH, 256, 0, stream>>>(sup, topBoxes, out);
}